// Round 2
// baseline (581.200 us; speedup 1.0000x reference)
//
#include <hip/hip_runtime.h>
#include <math.h>

#define H 128
#define BASKET 200
#define NGATHER 8            // gather blocks in K1
#define ROWS_PER_BLK 25      // 8 * 25 = 200
#define R3H (3 * H)          // 384

// ws layout (float offsets)
#define WS_PART 0            // [NGATHER][H] gather partial sums
#define WS_DUMP 4096         // warm-block DCE sink (32 floats)

// K1: blocks 0..7 do the embedding-bag gather (25 rows each, coalesced 512B
// row reads, all loads independent & in flight). Blocks 8..31 stream all
// 384 KB of GRU weights (+biases+hidden) so every XCD's L2 is warm for K2.
__global__ __launch_bounds__(256)
void k1_gather_warm(const int* __restrict__ basket,
                    const float* __restrict__ emb_table,
                    const float* __restrict__ w_ih,
                    const float* __restrict__ w_hh,
                    const float* __restrict__ b_ih,
                    const float* __restrict__ b_hh,
                    const float* __restrict__ hidden,
                    float* __restrict__ ws)
{
    const int b = blockIdx.x;
    const int t = threadIdx.x;

    if (b < NGATHER) {
        __shared__ int   s_idx[ROWS_PER_BLK];
        __shared__ float s_sub[2][H];
        if (t < ROWS_PER_BLK) s_idx[t] = basket[b * ROWS_PER_BLK + t];
        __syncthreads();
        const int h = t & (H - 1);
        const int c = t >> 7;               // 0 or 1
        const int lo = c ? 13 : 0;
        const int hi = c ? 25 : 13;
        float acc = 0.0f;
        for (int i = lo; i < hi; ++i)       // independent scattered row reads
            acc += emb_table[(size_t)s_idx[i] * H + h];
        s_sub[c][h] = acc;
        __syncthreads();
        if (t < H) ws[WS_PART + b * H + t] = s_sub[0][t] + s_sub[1][t];
    } else {
        // L2 warmer: touch every cache line of both weight matrices, the
        // biases, and hidden. Redundant across blocks on the same XCD, but
        // guarantees whichever XCD hosts K2 has everything resident.
        const float4* a4 = (const float4*)w_ih;
        const float4* b4 = (const float4*)w_hh;
        const int n4 = R3H * H / 4;         // 12288 float4 per matrix
        float4 acc = {0.f, 0.f, 0.f, 0.f};
        for (int i = t; i < n4; i += 256) {
            const float4 x = a4[i];
            const float4 y = b4[i];
            acc.x += x.x + y.x; acc.y += x.y + y.y;
            acc.z += x.z + y.z; acc.w += x.w + y.w;
        }
        float s = acc.x + acc.y + acc.z + acc.w;
        for (int i = t; i < R3H; i += 256) s += b_ih[i] + b_hh[i];
        if (t < H) s += hidden[t];
        ws[WS_DUMP + b] = s;                // keep the loads alive (4B write)
    }
}

// K2: reduce gather partials -> emb, both matvecs from L2-warm weights,
// GRU gate math, store both (identical) tuple outputs.
__global__ __launch_bounds__(768)
void k2_matvec_gates(const float* __restrict__ hidden,
                     const float* __restrict__ w_ih,
                     const float* __restrict__ w_hh,
                     const float* __restrict__ b_ih,
                     const float* __restrict__ b_hh,
                     const float* __restrict__ ws,
                     float* __restrict__ out)
{
    __shared__ __align__(16) float s_emb[H];
    __shared__ __align__(16) float s_h[H];
    __shared__ float s_gi[R3H];
    __shared__ float s_gh[R3H];

    const int t = threadIdx.x;

    if (t < H) {
        float s = 0.0f;
        #pragma unroll
        for (int b = 0; b < NGATHER; ++b) s += ws[WS_PART + b * H + t];
        s_emb[t] = s * (1.0f / (float)H);
        s_h[t]   = hidden[t];
    }
    __syncthreads();

    // 768 threads = 768 rows; split at t=384 (wave-6 boundary, wave-uniform).
    {
        const bool ih  = (t < R3H);
        const int  row = ih ? t : t - R3H;
        const float* __restrict__ w = ih ? w_ih : w_hh;
        const float4* __restrict__ w4 = (const float4*)(w + (size_t)row * H);
        const float4* __restrict__ v4 = (const float4*)(ih ? s_emb : s_h);
        float acc = ih ? b_ih[row] : b_hh[row];
        #pragma unroll
        for (int k = 0; k < H / 4; ++k) {
            const float4 wv = w4[k];
            const float4 vv = v4[k];
            acc += wv.x * vv.x + wv.y * vv.y + wv.z * vv.z + wv.w * vv.w;
        }
        if (ih) s_gi[row] = acc; else s_gh[row] = acc;
    }
    __syncthreads();

    if (t < H) {
        const float ir = s_gi[t], iz = s_gi[H + t], inn = s_gi[2 * H + t];
        const float hr = s_gh[t], hz = s_gh[H + t], hnn = s_gh[2 * H + t];
        const float r  = 1.0f / (1.0f + expf(-(ir + hr)));
        const float z  = 1.0f / (1.0f + expf(-(iz + hz)));
        const float n  = tanhf(inn + r * hnn);
        const float hv = s_h[t];
        const float hnew = (1.0f - z) * n + z * hv;
        out[t]     = hnew;
        out[H + t] = hnew;
    }
}

extern "C" void kernel_launch(void* const* d_in, const int* in_sizes, int n_in,
                              void* d_out, int out_size, void* d_ws, size_t ws_size,
                              hipStream_t stream) {
    const int*   basket    = (const int*)  d_in[0];
    const float* hidden    = (const float*)d_in[1];
    const float* emb_table = (const float*)d_in[2];
    const float* w_ih      = (const float*)d_in[3];
    const float* w_hh      = (const float*)d_in[4];
    const float* b_ih      = (const float*)d_in[5];
    const float* b_hh      = (const float*)d_in[6];
    float* out = (float*)d_out;
    float* ws  = (float*)d_ws;

    k1_gather_warm<<<32, 256, 0, stream>>>(basket, emb_table, w_ih, w_hh,
                                           b_ih, b_hh, hidden, ws);
    k2_matvec_gates<<<1, 768, 0, stream>>>(hidden, w_ih, w_hh, b_ih, b_hh,
                                           ws, out);
}